// Round 11
// baseline (530.748 us; speedup 1.0000x reference)
//
#include <hip/hip_runtime.h>

using u16 = unsigned short;
using u32 = unsigned int;
typedef __attribute__((ext_vector_type(8))) short bf16x8;
typedef __attribute__((ext_vector_type(4))) float f32x4;
typedef __attribute__((ext_vector_type(4))) float f4;

#define DIMC 1024
#define NQ 2048
#define NK 2048

static constexpr float LAMBDA_INIT = 0.6192834728526787f;  // 0.8 - 0.6*exp(-1.2)
static constexpr float ONE_MINUS_LI = 1.0f - 0.6192834728526787f;
static constexpr float SCALE_ = 0.17677669529663687f;      // 32^-0.5
static constexpr float LOG2E_ = 1.4426950408889634f;
static constexpr float EPS_ = 1e-5f;

__device__ __forceinline__ u16 f2bf(float f) {
    union { float f; unsigned u; } v; v.f = f;
    unsigned u = v.u;
    unsigned r = (u + 0x7FFFu + ((u >> 16) & 1u)) >> 16;
    return (u16)r;
}

// truncating pack of two f32 -> 2x bf16 (P is ratio-normalized; rel err 2^-8 cancels)
__device__ __forceinline__ u32 packbf_trunc(float a, float b) {
    return (__float_as_uint(a) >> 16) | (__float_as_uint(b) & 0xFFFF0000u);
}

// ---------------- fused f32 -> bf16 conversion for all 7 operands ----------------
// regions: q,k,v (4M elems each, 2048 blocks each), wq,wk,wv,wp (1M, 512 blocks each)
__global__ __launch_bounds__(256) void cvt_all_kernel(
    const float* __restrict__ q, const float* __restrict__ k, const float* __restrict__ v,
    const float* __restrict__ wq, const float* __restrict__ wk,
    const float* __restrict__ wv, const float* __restrict__ wp,
    u16* __restrict__ qo, u16* __restrict__ ko, u16* __restrict__ vo,
    u16* __restrict__ wqo, u16* __restrict__ wko, u16* __restrict__ wvo, u16* __restrict__ wpo)
{
    const int bid = blockIdx.x;
    const float* s; u16* d; int rb;
    if (bid < 6144) {
        const int r = bid >> 11;
        rb = bid & 2047;
        s = (r == 0) ? q : (r == 1) ? k : v;
        d = (r == 0) ? qo : (r == 1) ? ko : vo;
    } else {
        const int r = (bid - 6144) >> 9;
        rb = (bid - 6144) & 511;
        s = (r == 0) ? wq : (r == 1) ? wk : (r == 2) ? wv : wp;
        d = (r == 0) ? wqo : (r == 1) ? wko : (r == 2) ? wvo : wpo;
    }
    const size_t i = (size_t)rb * 2048 + threadIdx.x * 8;
    f4 a = *(const f4*)(s + i);
    f4 b = *(const f4*)(s + i + 4);
    bf16x8 r8;
    r8[0] = (short)f2bf(a[0]); r8[1] = (short)f2bf(a[1]);
    r8[2] = (short)f2bf(a[2]); r8[3] = (short)f2bf(a[3]);
    r8[4] = (short)f2bf(b[0]); r8[5] = (short)f2bf(b[1]);
    r8[6] = (short)f2bf(b[2]); r8[7] = (short)f2bf(b[3]);
    *(bf16x8*)(d + i) = r8;
}

// ---------------- 128x128-tile bf16 GEMM, direct global fragment loads ----------------
// C = A @ B^T.  A: M x 1024 bf16, B: N x 1024 bf16.
template<int OUT_MODE>  // 0: bf16 * osc, 1: f32 + bias
__device__ __forceinline__ void gemm_tile(
    const u16* __restrict__ A, const u16* __restrict__ B,
    void* __restrict__ C, const float* __restrict__ bias,
    int tm, int tn, int N, float osc)
{
    constexpr int K = 1024;
    const int lane = threadIdx.x & 63;
    const int wave = threadIdx.x >> 6;
    const int wr = wave >> 1, wc = wave & 1;
    const int l15 = lane & 15, l4 = lane >> 4;
    const int arow0 = tm + wr * 64, brow0 = tn + wc * 64;

    const u16* Ab = A + (size_t)(arow0 + l15) * K + 8 * l4;
    const u16* Bb = B + (size_t)(brow0 + l15) * K + 8 * l4;

    f32x4 acc[4][4];
    f32x4 zf = {0.f, 0.f, 0.f, 0.f};
#pragma unroll
    for (int i = 0; i < 4; ++i)
#pragma unroll
        for (int j = 0; j < 4; ++j) acc[i][j] = zf;

#pragma unroll 2
    for (int k0 = 0; k0 < K; k0 += 32) {
        bf16x8 af[4], bfr[4];
#pragma unroll
        for (int i = 0; i < 4; ++i) af[i] = *(const bf16x8*)(Ab + (size_t)i * 16 * K + k0);
#pragma unroll
        for (int j = 0; j < 4; ++j) bfr[j] = *(const bf16x8*)(Bb + (size_t)j * 16 * K + k0);
#pragma unroll
        for (int i = 0; i < 4; ++i)
#pragma unroll
            for (int j = 0; j < 4; ++j)
                acc[i][j] = __builtin_amdgcn_mfma_f32_16x16x32_bf16(af[i], bfr[j], acc[i][j], 0, 0, 0);
    }

#pragma unroll
    for (int i = 0; i < 4; ++i)
#pragma unroll
        for (int j = 0; j < 4; ++j)
#pragma unroll
            for (int r = 0; r < 4; ++r) {
                const int row = arow0 + i * 16 + l4 * 4 + r;
                const int col = brow0 + j * 16 + l15;
                const float v = acc[i][j][r];
                if (OUT_MODE == 0)
                    ((u16*)C)[(size_t)row * N + col] = f2bf(v * osc);
                else
                    ((float*)C)[(size_t)row * N + col] = v + bias[col];
            }
}

// fused Q/K/V projections (z selects), XCD-swizzled
__global__ __launch_bounds__(256) void qkv_gemm_kernel(
    const u16* __restrict__ qa, const u16* __restrict__ wq, u16* __restrict__ qo,
    const u16* __restrict__ ka, const u16* __restrict__ wk, u16* __restrict__ ko,
    const u16* __restrict__ wv, const u16* __restrict__ va, u16* __restrict__ vo,
    float qosc)
{
    int id = blockIdx.x + 8 * (blockIdx.y + 32 * blockIdx.z);  // 768 blocks
    id = (id & 7) * 96 + (id >> 3);                             // XCD-contiguous chunks
    const int x = id & 7, y = (id >> 3) & 31, z = id >> 8;

    if (z == 0)      gemm_tile<0>(qa, wq, qo, nullptr, y * 128, x * 128, 1024, qosc);
    else if (z == 1) gemm_tile<0>(ka, wk, ko, nullptr, y * 128, x * 128, 1024, 1.0f);
    else             gemm_tile<0>(wv, va, vo, nullptr, x * 128, y * 128, 4096, 1.0f);
}

__global__ __launch_bounds__(256) void out_gemm_kernel(
    const u16* __restrict__ A, const u16* __restrict__ Bw,
    float* __restrict__ C, const float* __restrict__ bias)
{
    int id = blockIdx.x + 8 * blockIdx.y;  // 256 blocks
    id = (id & 7) * 32 + (id >> 3);
    const int x = id & 7, y = id >> 3;
    gemm_tile<1>(A, Bw, C, bias, y * 128, x * 128, 1024, 1.0f);
}

// ---------------- differential flash attention + subln RMS epilogue ----------------
// 1-wave (64-thread) blocks: waves are fully independent (wave-private P LDS, no barriers),
// so small blocks let the CU pack ~20 wave-blocks for latency hiding.
// Qb: bf16 (pre-scaled by SCALE*log2e), Kb: bf16, Vt: bf16 [1024 dims][4096 tokens].
__global__ __launch_bounds__(64) void attn_kernel(
    const u16* __restrict__ Qb, const u16* __restrict__ Kb, const u16* __restrict__ Vt,
    const float* __restrict__ lq1, const float* __restrict__ lk1,
    const float* __restrict__ lq2, const float* __restrict__ lk2,
    const float* __restrict__ subln, u16* __restrict__ X2)
{
    const int lane = threadIdx.x & 63;
    const int l15 = lane & 15, l4 = lane >> 4;

    int id = blockIdx.x;                    // 4096 blocks
    id = (id & 7) * 512 + (id >> 3);        // 4 (b,h) groups per XCD
    const int qt = id & 127, h = (id >> 7) & 15, b = id >> 11;
    const int q0 = qt * 16;

    __shared__ alignas(16) u16 Ps[2][16 * 64];
    u16* P1 = &Ps[0][0];
    u16* P2 = &Ps[1][0];

    float s1 = 0.f, s2 = 0.f;
#pragma unroll
    for (int i = 0; i < 32; ++i) { s1 += lq1[i] * lk1[i]; s2 += lq2[i] * lk2[i]; }
    const float lam = __expf(s1) - __expf(s2) + LAMBDA_INIT;

    const u16* Qbase = Qb + (size_t)b * NQ * DIMC;
    const u16* Kbase = Kb + (size_t)b * NK * DIMC;
    const u16* Vbase = Vt + (size_t)h * 64 * 4096 + (size_t)b * 2048;

    const bf16x8 q1f = *(const bf16x8*)(Qbase + (size_t)(q0 + l15) * DIMC + h * 32 + 8 * l4);
    const bf16x8 q2f = *(const bf16x8*)(Qbase + (size_t)(q0 + l15) * DIMC + 512 + h * 32 + 8 * l4);

    float m1 = -1e30f, d1 = 0.f, m2 = -1e30f, d2 = 0.f;
    f32x4 acc1[4], acc2[4];
    f32x4 zf = {0.f, 0.f, 0.f, 0.f};
#pragma unroll
    for (int t = 0; t < 4; ++t) { acc1[t] = zf; acc2[t] = zf; }

    const int wrow = l4 << 2;

    for (int kv0 = 0; kv0 < NK; kv0 += 64) {
        // swapped QK^T (scores already in log2 domain via Q pre-scale)
        f32x4 sc1[4], sc2[4];
#pragma unroll
        for (int s = 0; s < 4; ++s) {
            const u16* kr = Kbase + (size_t)(kv0 + s * 16 + l15) * DIMC + 8 * l4;
            bf16x8 k1 = *(const bf16x8*)(kr + h * 32);
            bf16x8 k2 = *(const bf16x8*)(kr + 512 + h * 32);
            sc1[s] = __builtin_amdgcn_mfma_f32_16x16x32_bf16(k1, q1f, zf, 0, 0, 0);
            sc2[s] = __builtin_amdgcn_mfma_f32_16x16x32_bf16(k2, q2f, zf, 0, 0, 0);
        }

        // issue V loads early: independent of softmax, latency hides under exp chain
        bf16x8 vfr[2][4];
#pragma unroll
        for (int kc = 0; kc < 2; ++kc)
#pragma unroll
            for (int t = 0; t < 4; ++t)
                vfr[kc][t] = *(const bf16x8*)(Vbase + (size_t)(t * 16 + l15) * 4096 + kv0 + kc * 32 + 8 * l4);

        // ---- softmax attn 1 (defer-max, exp2) ----
        {
            float pm = sc1[0][0];
#pragma unroll
            for (int s = 0; s < 4; ++s)
#pragma unroll
                for (int r = 0; r < 4; ++r) pm = fmaxf(pm, sc1[s][r]);
            pm = fmaxf(pm, __shfl_xor(pm, 16));
            pm = fmaxf(pm, __shfl_xor(pm, 32));
            if (!__all(pm - m1 <= 8.f)) {
                const float mnew = fmaxf(m1, pm);
                const float alpha = __builtin_amdgcn_exp2f(m1 - mnew);
                m1 = mnew;
                d1 *= alpha;
                float ar[4];
#pragma unroll
                for (int r = 0; r < 4; ++r) ar[r] = __shfl(alpha, wrow + r);
#pragma unroll
                for (int t = 0; t < 4; ++t)
#pragma unroll
                    for (int r = 0; r < 4; ++r) acc1[t][r] *= ar[r];
            }
            float rs = 0.f;
            float p[4][4];
#pragma unroll
            for (int s = 0; s < 4; ++s)
#pragma unroll
                for (int r = 0; r < 4; ++r) {
                    p[s][r] = __builtin_amdgcn_exp2f(sc1[s][r] - m1);
                    rs += p[s][r];
                }
            rs += __shfl_xor(rs, 16);
            rs += __shfl_xor(rs, 32);
            d1 += rs;
#pragma unroll
            for (int s = 0; s < 4; ++s) {
                uint2 wv;
                wv.x = packbf_trunc(p[s][0], p[s][1]);
                wv.y = packbf_trunc(p[s][2], p[s][3]);
                const int idx = ((l15 << 6) + (s << 4) + (l4 << 2)) ^ ((l15 & 7) << 3);
                *(uint2*)&P1[idx] = wv;
            }
        }
        // ---- softmax attn 2 ----
        {
            float pm = sc2[0][0];
#pragma unroll
            for (int s = 0; s < 4; ++s)
#pragma unroll
                for (int r = 0; r < 4; ++r) pm = fmaxf(pm, sc2[s][r]);
            pm = fmaxf(pm, __shfl_xor(pm, 16));
            pm = fmaxf(pm, __shfl_xor(pm, 32));
            if (!__all(pm - m2 <= 8.f)) {
                const float mnew = fmaxf(m2, pm);
                const float alpha = __builtin_amdgcn_exp2f(m2 - mnew);
                m2 = mnew;
                d2 *= alpha;
                float ar[4];
#pragma unroll
                for (int r = 0; r < 4; ++r) ar[r] = __shfl(alpha, wrow + r);
#pragma unroll
                for (int t = 0; t < 4; ++t)
#pragma unroll
                    for (int r = 0; r < 4; ++r) acc2[t][r] *= ar[r];
            }
            float rs = 0.f;
            float p[4][4];
#pragma unroll
            for (int s = 0; s < 4; ++s)
#pragma unroll
                for (int r = 0; r < 4; ++r) {
                    p[s][r] = __builtin_amdgcn_exp2f(sc2[s][r] - m2);
                    rs += p[s][r];
                }
            rs += __shfl_xor(rs, 16);
            rs += __shfl_xor(rs, 32);
            d2 += rs;
#pragma unroll
            for (int s = 0; s < 4; ++s) {
                uint2 wv;
                wv.x = packbf_trunc(p[s][0], p[s][1]);
                wv.y = packbf_trunc(p[s][2], p[s][3]);
                const int idx = ((l15 << 6) + (s << 4) + (l4 << 2)) ^ ((l15 & 7) << 3);
                *(uint2*)&P2[idx] = wv;
            }
        }

        // ---- PV ----
#pragma unroll
        for (int kc = 0; kc < 2; ++kc) {
            const int ridx = ((l15 << 6) + (kc << 5) + (l4 << 3)) ^ ((l15 & 7) << 3);
            const bf16x8 p1a = *(const bf16x8*)&P1[ridx];
            const bf16x8 p2a = *(const bf16x8*)&P2[ridx];
#pragma unroll
            for (int t = 0; t < 4; ++t) {
                acc1[t] = __builtin_amdgcn_mfma_f32_16x16x32_bf16(p1a, vfr[kc][t], acc1[t], 0, 0, 0);
                acc2[t] = __builtin_amdgcn_mfma_f32_16x16x32_bf16(p2a, vfr[kc][t], acc2[t], 0, 0, 0);
            }
        }
    }

    // epilogue
    float i1[4], i2[4];
#pragma unroll
    for (int r = 0; r < 4; ++r) {
        i1[r] = 1.f / __shfl(d1, wrow + r);
        i2[r] = 1.f / __shfl(d2, wrow + r);
    }

    float vals[4][4];
    float ss[4] = {0.f, 0.f, 0.f, 0.f};
#pragma unroll
    for (int t = 0; t < 4; ++t)
#pragma unroll
        for (int r = 0; r < 4; ++r) {
            const float v = acc1[t][r] * i1[r] - lam * (acc2[t][r] * i2[r]);
            vals[t][r] = v;
            ss[r] += v * v;
        }
#pragma unroll
    for (int r = 0; r < 4; ++r) {
        float s = ss[r];
        s += __shfl_xor(s, 1); s += __shfl_xor(s, 2);
        s += __shfl_xor(s, 4); s += __shfl_xor(s, 8);
        ss[r] = rsqrtf(s * (1.f / 64.f) + EPS_) * ONE_MINUS_LI;
    }
#pragma unroll
    for (int t = 0; t < 4; ++t)
#pragma unroll
        for (int r = 0; r < 4; ++r) {
            const int col = t * 16 + l15;
            const int row = q0 + wrow + r;
            const float o = vals[t][r] * ss[r] * subln[col];
            X2[(size_t)(b * NQ + row) * DIMC + h * 64 + col] = f2bf(o);
        }
}

extern "C" void kernel_launch(void* const* d_in, const int* in_sizes, int n_in,
                              void* d_out, int out_size, void* d_ws, size_t ws_size,
                              hipStream_t stream) {
    const float* query = (const float*)d_in[0];
    const float* key_  = (const float*)d_in[1];
    const float* value = (const float*)d_in[2];
    const float* Wq    = (const float*)d_in[3];
    const float* Wk    = (const float*)d_in[4];
    const float* Wv    = (const float*)d_in[5];
    const float* Wp    = (const float*)d_in[6];
    const float* bp    = (const float*)d_in[7];
    const float* lq1   = (const float*)d_in[8];
    const float* lk1   = (const float*)d_in[9];
    const float* lq2   = (const float*)d_in[10];
    const float* lk2   = (const float*)d_in[11];
    const float* subln = (const float*)d_in[12];
    float* out = (float*)d_out;

    const size_t MB4 = (size_t)4096 * 1024;   // 4M elems
    const size_t MB1 = (size_t)1024 * 1024;   // 1M elems
    u16* base = (u16*)d_ws;
    u16* qbf = base;                 // 4M
    u16* kbf = qbf + MB4;            // 4M
    u16* vbf = kbf + MB4;            // 4M  (reused as X2 after QKV gemm)
    u16* wqb = vbf + MB4;            // 1M
    u16* wkb = wqb + MB1;            // 1M
    u16* wvb = wkb + MB1;            // 1M
    u16* wpb = wvb + MB1;            // 1M
    u16* Qb  = wpb + MB1;            // 4M
    u16* Kb  = Qb + MB4;             // 4M
    u16* Vt  = Kb + MB4;             // 4M  [1024 dims][4096 tokens]
    u16* X2  = vbf;                  // alias: vbf dead after qkv gemm

    dim3 bb(256, 1, 1);
    // all f32 -> bf16 conversions in one launch
    hipLaunchKernelGGL(cvt_all_kernel, dim3(8192), bb, 0, stream,
                       query, key_, value, Wq, Wk, Wv, Wp,
                       qbf, kbf, vbf, wqb, wkb, wvb, wpb);

    // fused QKV projections (Q pre-scaled by SCALE*log2e); V transposed via swapped operands
    hipLaunchKernelGGL(qkv_gemm_kernel, dim3(8, 32, 3), bb, 0, stream,
                       qbf, wqb, Qb, kbf, wkb, Kb, wvb, vbf, Vt, SCALE_ * LOG2E_);

    hipLaunchKernelGGL(attn_kernel, dim3(4096), dim3(64), 0, stream,
                       Qb, Kb, Vt, lq1, lk1, lq2, lk2, subln, X2);

    hipLaunchKernelGGL(out_gemm_kernel, dim3(8, 32, 1), bb, 0, stream, X2, wpb, out, bp);
}

// Round 13
// 385.315 us; speedup vs baseline: 1.3774x; 1.3774x over previous
//
#include <hip/hip_runtime.h>

using u16 = unsigned short;
using u32 = unsigned int;
typedef __attribute__((ext_vector_type(8))) short bf16x8;
typedef __attribute__((ext_vector_type(4))) float f32x4;
typedef __attribute__((ext_vector_type(4))) float f4;

#define DIMC 1024
#define NQ 2048
#define NK 2048

static constexpr float LAMBDA_INIT = 0.6192834728526787f;  // 0.8 - 0.6*exp(-1.2)
static constexpr float ONE_MINUS_LI = 1.0f - 0.6192834728526787f;
static constexpr float SCALE_ = 0.17677669529663687f;      // 32^-0.5
static constexpr float LOG2E_ = 1.4426950408889634f;
static constexpr float EPS_ = 1e-5f;

__device__ __forceinline__ u16 f2bf(float f) {
    union { float f; unsigned u; } v; v.f = f;
    unsigned u = v.u;
    unsigned r = (u + 0x7FFFu + ((u >> 16) & 1u)) >> 16;
    return (u16)r;
}

// truncating pack of two f32 -> 2x bf16 (P is ratio-normalized; rel err 2^-8 cancels)
__device__ __forceinline__ u32 packbf_trunc(float a, float b) {
    return (__float_as_uint(a) >> 16) | (__float_as_uint(b) & 0xFFFF0000u);
}

// async global -> LDS, 16B per lane. LDS dest is wave-uniform base + lane*16.
__device__ __forceinline__ void gload_lds16(const u16* g, u16* l) {
    __builtin_amdgcn_global_load_lds(
        (const __attribute__((address_space(1))) unsigned int*)g,
        (__attribute__((address_space(3))) unsigned int*)l,
        16, 0, 0);
}

// ---------------- fused f32 -> bf16 conversion for all 7 operands ----------------
__global__ __launch_bounds__(256) void cvt_all_kernel(
    const float* __restrict__ q, const float* __restrict__ k, const float* __restrict__ v,
    const float* __restrict__ wq, const float* __restrict__ wk,
    const float* __restrict__ wv, const float* __restrict__ wp,
    u16* __restrict__ qo, u16* __restrict__ ko, u16* __restrict__ vo,
    u16* __restrict__ wqo, u16* __restrict__ wko, u16* __restrict__ wvo, u16* __restrict__ wpo)
{
    const int bid = blockIdx.x;
    const float* s; u16* d; int rb;
    if (bid < 6144) {
        const int r = bid >> 11;
        rb = bid & 2047;
        s = (r == 0) ? q : (r == 1) ? k : v;
        d = (r == 0) ? qo : (r == 1) ? ko : vo;
    } else {
        const int r = (bid - 6144) >> 9;
        rb = (bid - 6144) & 511;
        s = (r == 0) ? wq : (r == 1) ? wk : (r == 2) ? wv : wp;
        d = (r == 0) ? wqo : (r == 1) ? wko : (r == 2) ? wvo : wpo;
    }
    const size_t i = (size_t)rb * 2048 + threadIdx.x * 8;
    f4 a = *(const f4*)(s + i);
    f4 b = *(const f4*)(s + i + 4);
    bf16x8 r8;
    r8[0] = (short)f2bf(a[0]); r8[1] = (short)f2bf(a[1]);
    r8[2] = (short)f2bf(a[2]); r8[3] = (short)f2bf(a[3]);
    r8[4] = (short)f2bf(b[0]); r8[5] = (short)f2bf(b[1]);
    r8[6] = (short)f2bf(b[2]); r8[7] = (short)f2bf(b[3]);
    *(bf16x8*)(d + i) = r8;
}

// ---------------- 128x128-tile bf16 GEMM, direct global fragment loads ----------------
template<int OUT_MODE>  // 0: bf16 * osc, 1: f32 + bias
__device__ __forceinline__ void gemm_tile(
    const u16* __restrict__ A, const u16* __restrict__ B,
    void* __restrict__ C, const float* __restrict__ bias,
    int tm, int tn, int N, float osc)
{
    constexpr int K = 1024;
    const int lane = threadIdx.x & 63;
    const int wave = threadIdx.x >> 6;
    const int wr = wave >> 1, wc = wave & 1;
    const int l15 = lane & 15, l4 = lane >> 4;
    const int arow0 = tm + wr * 64, brow0 = tn + wc * 64;

    const u16* Ab = A + (size_t)(arow0 + l15) * K + 8 * l4;
    const u16* Bb = B + (size_t)(brow0 + l15) * K + 8 * l4;

    f32x4 acc[4][4];
    f32x4 zf = {0.f, 0.f, 0.f, 0.f};
#pragma unroll
    for (int i = 0; i < 4; ++i)
#pragma unroll
        for (int j = 0; j < 4; ++j) acc[i][j] = zf;

#pragma unroll 2
    for (int k0 = 0; k0 < K; k0 += 32) {
        bf16x8 af[4], bfr[4];
#pragma unroll
        for (int i = 0; i < 4; ++i) af[i] = *(const bf16x8*)(Ab + (size_t)i * 16 * K + k0);
#pragma unroll
        for (int j = 0; j < 4; ++j) bfr[j] = *(const bf16x8*)(Bb + (size_t)j * 16 * K + k0);
#pragma unroll
        for (int i = 0; i < 4; ++i)
#pragma unroll
            for (int j = 0; j < 4; ++j)
                acc[i][j] = __builtin_amdgcn_mfma_f32_16x16x32_bf16(af[i], bfr[j], acc[i][j], 0, 0, 0);
    }

#pragma unroll
    for (int i = 0; i < 4; ++i)
#pragma unroll
        for (int j = 0; j < 4; ++j)
#pragma unroll
            for (int r = 0; r < 4; ++r) {
                const int row = arow0 + i * 16 + l4 * 4 + r;
                const int col = brow0 + j * 16 + l15;
                const float v = acc[i][j][r];
                if (OUT_MODE == 0)
                    ((u16*)C)[(size_t)row * N + col] = f2bf(v * osc);
                else
                    ((float*)C)[(size_t)row * N + col] = v + bias[col];
            }
}

// fused Q/K/V projections (z selects), XCD-swizzled
__global__ __launch_bounds__(256) void qkv_gemm_kernel(
    const u16* __restrict__ qa, const u16* __restrict__ wq, u16* __restrict__ qo,
    const u16* __restrict__ ka, const u16* __restrict__ wk, u16* __restrict__ ko,
    const u16* __restrict__ wv, const u16* __restrict__ va, u16* __restrict__ vo,
    float qosc)
{
    int id = blockIdx.x + 8 * (blockIdx.y + 32 * blockIdx.z);  // 768 blocks
    id = (id & 7) * 96 + (id >> 3);                             // XCD-contiguous chunks
    const int x = id & 7, y = (id >> 3) & 31, z = id >> 8;

    if (z == 0)      gemm_tile<0>(qa, wq, qo, nullptr, y * 128, x * 128, 1024, qosc);
    else if (z == 1) gemm_tile<0>(ka, wk, ko, nullptr, y * 128, x * 128, 1024, 1.0f);
    else             gemm_tile<0>(wv, va, vo, nullptr, x * 128, y * 128, 4096, 1.0f);
}

__global__ __launch_bounds__(256) void out_gemm_kernel(
    const u16* __restrict__ A, const u16* __restrict__ Bw,
    float* __restrict__ C, const float* __restrict__ bias)
{
    int id = blockIdx.x + 8 * blockIdx.y;  // 256 blocks
    id = (id & 7) * 32 + (id >> 3);
    const int x = id & 7, y = id >> 3;
    gemm_tile<1>(A, Bw, C, bias, y * 128, x * 128, 1024, 1.0f);
}

// ---------------- differential flash attention + subln RMS epilogue ----------------
// 4-wave blocks; block = 64 q-rows of one (b,h). K/V tiles staged once per block into
// LDS via async global_load_lds (double-buffered 2-phase), chunk-transposed layout:
//   L(row, chunk16) = chunk16*1024B + row*16B   (linear DMA dest == fragment-read layout,
//   consecutive lanes hit consecutive 16B slots -> conflict-free ds_read_b128).
// Qb: bf16 (pre-scaled by SCALE*log2e), Kb: bf16, Vt: bf16 [1024 dims][4096 tokens].
__global__ __launch_bounds__(256) void attn_kernel(
    const u16* __restrict__ Qb, const u16* __restrict__ Kb, const u16* __restrict__ Vt,
    const float* __restrict__ lq1, const float* __restrict__ lk1,
    const float* __restrict__ lq2, const float* __restrict__ lk2,
    const float* __restrict__ subln, u16* __restrict__ X2)
{
    const int tid = threadIdx.x;
    const int lane = tid & 63;
    const int wv = tid >> 6;
    const int l15 = lane & 15, l4 = lane >> 4;

    int id = blockIdx.x;                    // 1024 blocks
    id = (id & 7) * 128 + (id >> 3);        // 4 (b,h) groups per XCD (K/V ~2MB, L2-fit)
    const int qt = id & 31, h = (id >> 5) & 15, b = id >> 9;
    const int q0 = qt * 64 + wv * 16;

    __shared__ alignas(16) u16 Kbuf[2][4096];   // 8KB x2: 8 chunks x (64 rows x 8 u16)
    __shared__ alignas(16) u16 Vbuf[2][4096];   // 8KB x2
    __shared__ alignas(16) u16 Ps[4][2][1024];  // per-wave P tiles
    u16* P1 = &Ps[wv][0][0];
    u16* P2 = &Ps[wv][1][0];

    float s1 = 0.f, s2 = 0.f;
#pragma unroll
    for (int i = 0; i < 32; ++i) { s1 += lq1[i] * lk1[i]; s2 += lq2[i] * lk2[i]; }
    const float lam = __expf(s1) - __expf(s2) + LAMBDA_INIT;

    const u16* Qbase = Qb + (size_t)b * NQ * DIMC;
    // per-lane staging source bases (row/dim = lane)
    const u16* Krow = Kb + (size_t)b * NK * DIMC + (size_t)lane * DIMC + h * 32;
    const u16* Vrow = Vt + (size_t)h * 64 * 4096 + (size_t)b * 2048 + (size_t)lane * 4096;

    const bf16x8 q1f = *(const bf16x8*)(Qbase + (size_t)(q0 + l15) * DIMC + h * 32 + 8 * l4);
    const bf16x8 q2f = *(const bf16x8*)(Qbase + (size_t)(q0 + l15) * DIMC + 512 + h * 32 + 8 * l4);

    float m1 = -1e30f, d1 = 0.f, m2 = -1e30f, d2 = 0.f;
    f32x4 acc1[4], acc2[4];
    f32x4 zf = {0.f, 0.f, 0.f, 0.f};
#pragma unroll
    for (int t = 0; t < 4; ++t) { acc1[t] = zf; acc2[t] = zf; }

    const int wrow = l4 << 2;

    // stage tile at kv into buffer nb (async; each wave covers chunks {wv, 4+wv})
    auto STAGE = [&](int nb, int kv) {
#pragma unroll
        for (int g = 0; g < 2; ++g) {
            const int c = g * 4 + wv;
            const int koff = (c < 4) ? c * 8 : 512 + (c - 4) * 8;
            gload_lds16(Krow + (size_t)kv * DIMC + koff, &Kbuf[nb][c * 512]);
            gload_lds16(Vrow + kv + c * 8,               &Vbuf[nb][c * 512]);
        }
    };

    STAGE(0, 0);
    __syncthreads();   // compiler drains vmcnt before s_barrier -> tile 0 staged

    int buf = 0;
    for (int t = 0; t < 32; ++t) {
        if (t < 31) STAGE(buf ^ 1, (t + 1) * 64);   // async prefetch next tile

        const u16* Kl = &Kbuf[buf][0];
        const u16* Vl = &Vbuf[buf][0];

        // swapped QK^T from LDS (scores in log2 domain via Q pre-scale)
        f32x4 sc1[4], sc2[4];
#pragma unroll
        for (int s = 0; s < 4; ++s) {
            bf16x8 k1 = *(const bf16x8*)(Kl + l4 * 512 + (s * 16 + l15) * 8);
            bf16x8 k2 = *(const bf16x8*)(Kl + (4 + l4) * 512 + (s * 16 + l15) * 8);
            sc1[s] = __builtin_amdgcn_mfma_f32_16x16x32_bf16(k1, q1f, zf, 0, 0, 0);
            sc2[s] = __builtin_amdgcn_mfma_f32_16x16x32_bf16(k2, q2f, zf, 0, 0, 0);
        }

        // ---- softmax attn 1 (defer-max, exp2) ----
        {
            float pm = sc1[0][0];
#pragma unroll
            for (int s = 0; s < 4; ++s)
#pragma unroll
                for (int r = 0; r < 4; ++r) pm = fmaxf(pm, sc1[s][r]);
            pm = fmaxf(pm, __shfl_xor(pm, 16));
            pm = fmaxf(pm, __shfl_xor(pm, 32));
            if (!__all(pm - m1 <= 8.f)) {
                const float mnew = fmaxf(m1, pm);
                const float alpha = __builtin_amdgcn_exp2f(m1 - mnew);
                m1 = mnew;
                d1 *= alpha;
                float ar[4];
#pragma unroll
                for (int r = 0; r < 4; ++r) ar[r] = __shfl(alpha, wrow + r);
#pragma unroll
                for (int tt = 0; tt < 4; ++tt)
#pragma unroll
                    for (int r = 0; r < 4; ++r) acc1[tt][r] *= ar[r];
            }
            float rs = 0.f;
            float p[4][4];
#pragma unroll
            for (int s = 0; s < 4; ++s)
#pragma unroll
                for (int r = 0; r < 4; ++r) {
                    p[s][r] = __builtin_amdgcn_exp2f(sc1[s][r] - m1);
                    rs += p[s][r];
                }
            rs += __shfl_xor(rs, 16);
            rs += __shfl_xor(rs, 32);
            d1 += rs;
#pragma unroll
            for (int s = 0; s < 4; ++s) {
                uint2 wvv;
                wvv.x = packbf_trunc(p[s][0], p[s][1]);
                wvv.y = packbf_trunc(p[s][2], p[s][3]);
                const int idx = ((l15 << 6) + (s << 4) + (l4 << 2)) ^ ((l15 & 7) << 3);
                *(uint2*)&P1[idx] = wvv;
            }
        }
        // ---- softmax attn 2 ----
        {
            float pm = sc2[0][0];
#pragma unroll
            for (int s = 0; s < 4; ++s)
#pragma unroll
                for (int r = 0; r < 4; ++r) pm = fmaxf(pm, sc2[s][r]);
            pm = fmaxf(pm, __shfl_xor(pm, 16));
            pm = fmaxf(pm, __shfl_xor(pm, 32));
            if (!__all(pm - m2 <= 8.f)) {
                const float mnew = fmaxf(m2, pm);
                const float alpha = __builtin_amdgcn_exp2f(m2 - mnew);
                m2 = mnew;
                d2 *= alpha;
                float ar[4];
#pragma unroll
                for (int r = 0; r < 4; ++r) ar[r] = __shfl(alpha, wrow + r);
#pragma unroll
                for (int tt = 0; tt < 4; ++tt)
#pragma unroll
                    for (int r = 0; r < 4; ++r) acc2[tt][r] *= ar[r];
            }
            float rs = 0.f;
            float p[4][4];
#pragma unroll
            for (int s = 0; s < 4; ++s)
#pragma unroll
                for (int r = 0; r < 4; ++r) {
                    p[s][r] = __builtin_amdgcn_exp2f(sc2[s][r] - m2);
                    rs += p[s][r];
                }
            rs += __shfl_xor(rs, 16);
            rs += __shfl_xor(rs, 32);
            d2 += rs;
#pragma unroll
            for (int s = 0; s < 4; ++s) {
                uint2 wvv;
                wvv.x = packbf_trunc(p[s][0], p[s][1]);
                wvv.y = packbf_trunc(p[s][2], p[s][3]);
                const int idx = ((l15 << 6) + (s << 4) + (l4 << 2)) ^ ((l15 & 7) << 3);
                *(uint2*)&P2[idx] = wvv;
            }
        }

        // ---- PV from LDS ----
#pragma unroll
        for (int kc = 0; kc < 2; ++kc) {
            const int ridx = ((l15 << 6) + (kc << 5) + (l4 << 3)) ^ ((l15 & 7) << 3);
            const bf16x8 p1a = *(const bf16x8*)&P1[ridx];
            const bf16x8 p2a = *(const bf16x8*)&P2[ridx];
#pragma unroll
            for (int tt = 0; tt < 4; ++tt) {
                bf16x8 vb = *(const bf16x8*)(Vl + (kc * 4 + l4) * 512 + (tt * 16 + l15) * 8);
                acc1[tt] = __builtin_amdgcn_mfma_f32_16x16x32_bf16(p1a, vb, acc1[tt], 0, 0, 0);
                acc2[tt] = __builtin_amdgcn_mfma_f32_16x16x32_bf16(p2a, vb, acc2[tt], 0, 0, 0);
            }
        }

        __syncthreads();   // drain staging vmcnt + sync waves; next tile ready
        buf ^= 1;
    }

    // epilogue
    float i1[4], i2[4];
#pragma unroll
    for (int r = 0; r < 4; ++r) {
        i1[r] = 1.f / __shfl(d1, wrow + r);
        i2[r] = 1.f / __shfl(d2, wrow + r);
    }

    float vals[4][4];
    float ss[4] = {0.f, 0.f, 0.f, 0.f};
#pragma unroll
    for (int t = 0; t < 4; ++t)
#pragma unroll
        for (int r = 0; r < 4; ++r) {
            const float v = acc1[t][r] * i1[r] - lam * (acc2[t][r] * i2[r]);
            vals[t][r] = v;
            ss[r] += v * v;
        }
#pragma unroll
    for (int r = 0; r < 4; ++r) {
        float s = ss[r];
        s += __shfl_xor(s, 1); s += __shfl_xor(s, 2);
        s += __shfl_xor(s, 4); s += __shfl_xor(s, 8);
        ss[r] = rsqrtf(s * (1.f / 64.f) + EPS_) * ONE_MINUS_LI;
    }
#pragma unroll
    for (int t = 0; t < 4; ++t)
#pragma unroll
        for (int r = 0; r < 4; ++r) {
            const int col = t * 16 + l15;
            const int row = q0 + wrow + r;
            const float o = vals[t][r] * ss[r] * subln[col];
            X2[(size_t)(b * NQ + row) * DIMC + h * 64 + col] = f2bf(o);
        }
}

extern "C" void kernel_launch(void* const* d_in, const int* in_sizes, int n_in,
                              void* d_out, int out_size, void* d_ws, size_t ws_size,
                              hipStream_t stream) {
    const float* query = (const float*)d_in[0];
    const float* key_  = (const float*)d_in[1];
    const float* value = (const float*)d_in[2];
    const float* Wq    = (const float*)d_in[3];
    const float* Wk    = (const float*)d_in[4];
    const float* Wv    = (const float*)d_in[5];
    const float* Wp    = (const float*)d_in[6];
    const float* bp    = (const float*)d_in[7];
    const float* lq1   = (const float*)d_in[8];
    const float* lk1   = (const float*)d_in[9];
    const float* lq2   = (const float*)d_in[10];
    const float* lk2   = (const float*)d_in[11];
    const float* subln = (const float*)d_in[12];
    float* out = (float*)d_out;

    const size_t MB4 = (size_t)4096 * 1024;   // 4M elems
    const size_t MB1 = (size_t)1024 * 1024;   // 1M elems
    u16* base = (u16*)d_ws;
    u16* qbf = base;                 // 4M
    u16* kbf = qbf + MB4;            // 4M
    u16* vbf = kbf + MB4;            // 4M  (reused as X2 after QKV gemm)
    u16* wqb = vbf + MB4;            // 1M
    u16* wkb = wqb + MB1;            // 1M
    u16* wvb = wkb + MB1;            // 1M
    u16* wpb = wvb + MB1;            // 1M
    u16* Qb  = wpb + MB1;            // 4M
    u16* Kb  = Qb + MB4;             // 4M
    u16* Vt  = Kb + MB4;             // 4M  [1024 dims][4096 tokens]
    u16* X2  = vbf;                  // alias: vbf dead after qkv gemm

    dim3 bb(256, 1, 1);
    // all f32 -> bf16 conversions in one launch
    hipLaunchKernelGGL(cvt_all_kernel, dim3(8192), bb, 0, stream,
                       query, key_, value, Wq, Wk, Wv, Wp,
                       qbf, kbf, vbf, wqb, wkb, wvb, wpb);

    // fused QKV projections (Q pre-scaled by SCALE*log2e); V transposed via swapped operands
    hipLaunchKernelGGL(qkv_gemm_kernel, dim3(8, 32, 3), bb, 0, stream,
                       qbf, wqb, Qb, kbf, wkb, Kb, wvb, vbf, Vt, SCALE_ * LOG2E_);

    hipLaunchKernelGGL(attn_kernel, dim3(1024), bb, 0, stream,
                       Qb, Kb, Vt, lq1, lk1, lq2, lk2, subln, X2);

    hipLaunchKernelGGL(out_gemm_kernel, dim3(8, 32, 1), bb, 0, stream, X2, wpb, out, bp);
}

// Round 14
// 334.585 us; speedup vs baseline: 1.5863x; 1.1516x over previous
//
#include <hip/hip_runtime.h>

using u16 = unsigned short;
using u32 = unsigned int;
typedef __attribute__((ext_vector_type(8))) short bf16x8;
typedef __attribute__((ext_vector_type(4))) float f32x4;
typedef __attribute__((ext_vector_type(4))) float f4;

#define DIMC 1024
#define NQ 2048
#define NK 2048

static constexpr float LAMBDA_INIT = 0.6192834728526787f;  // 0.8 - 0.6*exp(-1.2)
static constexpr float ONE_MINUS_LI = 1.0f - 0.6192834728526787f;
static constexpr float SCALE_ = 0.17677669529663687f;      // 32^-0.5
static constexpr float LOG2E_ = 1.4426950408889634f;
static constexpr float EPS_ = 1e-5f;

__device__ __forceinline__ u16 f2bf(float f) {
    union { float f; unsigned u; } v; v.f = f;
    unsigned u = v.u;
    unsigned r = (u + 0x7FFFu + ((u >> 16) & 1u)) >> 16;
    return (u16)r;
}

__device__ __forceinline__ u32 packbf_trunc(float a, float b) {
    return (__float_as_uint(a) >> 16) | (__float_as_uint(b) & 0xFFFF0000u);
}

// async global -> LDS, 16B per lane. LDS dest: wave-uniform base (+ implicit lane*16).
__device__ __forceinline__ void gload_lds16(const u16* g, u16* l) {
    __builtin_amdgcn_global_load_lds(
        (const __attribute__((address_space(1))) unsigned int*)g,
        (__attribute__((address_space(3))) unsigned int*)l,
        16, 0, 0);
}

// ---------------- fused f32 -> bf16 conversion for all 7 operands ----------------
__global__ __launch_bounds__(256) void cvt_all_kernel(
    const float* __restrict__ q, const float* __restrict__ k, const float* __restrict__ v,
    const float* __restrict__ wq, const float* __restrict__ wk,
    const float* __restrict__ wv, const float* __restrict__ wp,
    u16* __restrict__ qo, u16* __restrict__ ko, u16* __restrict__ vo,
    u16* __restrict__ wqo, u16* __restrict__ wko, u16* __restrict__ wvo, u16* __restrict__ wpo)
{
    const int bid = blockIdx.x;
    const float* s; u16* d; int rb;
    if (bid < 6144) {
        const int r = bid >> 11;
        rb = bid & 2047;
        s = (r == 0) ? q : (r == 1) ? k : v;
        d = (r == 0) ? qo : (r == 1) ? ko : vo;
    } else {
        const int r = (bid - 6144) >> 9;
        rb = (bid - 6144) & 511;
        s = (r == 0) ? wq : (r == 1) ? wk : (r == 2) ? wv : wp;
        d = (r == 0) ? wqo : (r == 1) ? wko : (r == 2) ? wvo : wpo;
    }
    const size_t i = (size_t)rb * 2048 + threadIdx.x * 8;
    f4 a = *(const f4*)(s + i);
    f4 b = *(const f4*)(s + i + 4);
    bf16x8 r8;
    r8[0] = (short)f2bf(a[0]); r8[1] = (short)f2bf(a[1]);
    r8[2] = (short)f2bf(a[2]); r8[3] = (short)f2bf(a[3]);
    r8[4] = (short)f2bf(b[0]); r8[5] = (short)f2bf(b[1]);
    r8[6] = (short)f2bf(b[2]); r8[7] = (short)f2bf(b[3]);
    *(bf16x8*)(d + i) = r8;
}

// ---------------- LDS-staged 128x128 bf16 GEMM (m97 structure) ----------------
// C = A @ B^T. A: (tm..tm+128) x 1024, B: (tn..tn+128) x 1024, both bf16.
// LDS layout per buffer: chunk-major slots: slot = kchunk*128 + row, 16B each.
// Staged via global_load_lds (wave-uniform dest, per-lane global src) -> DMA order
// equals read layout by construction (conflict-benign ds_read_b128 fragments).
template<int OUT_MODE>  // 0: bf16 * osc, 1: f32 + bias
__device__ __forceinline__ void gemm_tile_staged(
    u16 (*Ab)[4096], u16 (*Bb)[4096],
    const u16* __restrict__ A, const u16* __restrict__ B,
    void* __restrict__ C, const float* __restrict__ bias,
    int tm, int tn, int N, float osc)
{
    constexpr int K = 1024;
    const int tid = threadIdx.x;
    const int lane = tid & 63;
    const int wv = tid >> 6;
    const int wr = wv >> 1, wc = wv & 1;
    const int l15 = lane & 15, l4 = lane >> 4;

    // stage K-step k0 into buffer nb: 2 issues x 2 operands per thread
    auto STAGE = [&](int nb, int k0) {
#pragma unroll
        for (int g = 0; g < 2; ++g) {
            const int sbase = g * 256 + wv * 64;       // wave-uniform slot base
            const int slot = sbase + lane;             // per-lane (for global src)
            const int c = slot >> 7, row = slot & 127;
            gload_lds16(A + (size_t)(tm + row) * K + k0 + c * 8, &Ab[nb][sbase * 8]);
            gload_lds16(B + (size_t)(tn + row) * K + k0 + c * 8, &Bb[nb][sbase * 8]);
        }
    };

    f32x4 acc[4][4];
    f32x4 zf = {0.f, 0.f, 0.f, 0.f};
#pragma unroll
    for (int i = 0; i < 4; ++i)
#pragma unroll
        for (int j = 0; j < 4; ++j) acc[i][j] = zf;

    STAGE(0, 0);
    __syncthreads();   // vmcnt drained before barrier -> tile 0 staged

    int buf = 0;
    for (int t = 0; t < 32; ++t) {
        if (t < 31) STAGE(buf ^ 1, (t + 1) * 32);   // async prefetch next K-step

        bf16x8 af[4], bfr[4];
#pragma unroll
        for (int i = 0; i < 4; ++i)
            af[i] = *(const bf16x8*)&Ab[buf][l4 * 1024 + (wr * 64 + i * 16 + l15) * 8];
#pragma unroll
        for (int j = 0; j < 4; ++j)
            bfr[j] = *(const bf16x8*)&Bb[buf][l4 * 1024 + (wc * 64 + j * 16 + l15) * 8];
#pragma unroll
        for (int i = 0; i < 4; ++i)
#pragma unroll
            for (int j = 0; j < 4; ++j)
                acc[i][j] = __builtin_amdgcn_mfma_f32_16x16x32_bf16(af[i], bfr[j], acc[i][j], 0, 0, 0);

        __syncthreads();   // reads done + prefetch drained; swap
        buf ^= 1;
    }

#pragma unroll
    for (int i = 0; i < 4; ++i)
#pragma unroll
        for (int j = 0; j < 4; ++j)
#pragma unroll
            for (int r = 0; r < 4; ++r) {
                const int row = tm + wr * 64 + i * 16 + l4 * 4 + r;
                const int col = tn + wc * 64 + j * 16 + l15;
                const float v = acc[i][j][r];
                if (OUT_MODE == 0)
                    ((u16*)C)[(size_t)row * N + col] = f2bf(v * osc);
                else
                    ((float*)C)[(size_t)row * N + col] = v + bias[col];
            }
}

// fused Q/K/V projections (z selects), XCD-swizzled
__global__ __launch_bounds__(256) void qkv_gemm_kernel(
    const u16* __restrict__ qa, const u16* __restrict__ wq, u16* __restrict__ qo,
    const u16* __restrict__ ka, const u16* __restrict__ wk, u16* __restrict__ ko,
    const u16* __restrict__ wv, const u16* __restrict__ va, u16* __restrict__ vo,
    float qosc)
{
    __shared__ alignas(16) u16 Ab[2][4096];
    __shared__ alignas(16) u16 Bb[2][4096];

    int id = blockIdx.x + 8 * (blockIdx.y + 32 * blockIdx.z);  // 768 blocks
    id = (id & 7) * 96 + (id >> 3);                             // XCD-contiguous chunks
    const int x = id & 7, y = (id >> 3) & 31, z = id >> 8;

    if (z == 0)      gemm_tile_staged<0>(Ab, Bb, qa, wq, qo, nullptr, y * 128, x * 128, 1024, qosc);
    else if (z == 1) gemm_tile_staged<0>(Ab, Bb, ka, wk, ko, nullptr, y * 128, x * 128, 1024, 1.0f);
    else             gemm_tile_staged<0>(Ab, Bb, wv, va, vo, nullptr, x * 128, y * 128, 4096, 1.0f);
}

__global__ __launch_bounds__(256) void out_gemm_kernel(
    const u16* __restrict__ A, const u16* __restrict__ Bw,
    float* __restrict__ C, const float* __restrict__ bias)
{
    __shared__ alignas(16) u16 Ab[2][4096];
    __shared__ alignas(16) u16 Bb[2][4096];

    int id = blockIdx.x + 8 * blockIdx.y;  // 256 blocks
    id = (id & 7) * 32 + (id >> 3);
    const int x = id & 7, y = id >> 3;
    gemm_tile_staged<1>(Ab, Bb, A, Bw, C, bias, y * 128, x * 128, 1024, 1.0f);
}

// ---------------- differential flash attention + subln RMS epilogue ----------------
// (unchanged from round 13 — 149 us, prediction-validated)
__global__ __launch_bounds__(256) void attn_kernel(
    const u16* __restrict__ Qb, const u16* __restrict__ Kb, const u16* __restrict__ Vt,
    const float* __restrict__ lq1, const float* __restrict__ lk1,
    const float* __restrict__ lq2, const float* __restrict__ lk2,
    const float* __restrict__ subln, u16* __restrict__ X2)
{
    const int tid = threadIdx.x;
    const int lane = tid & 63;
    const int wv = tid >> 6;
    const int l15 = lane & 15, l4 = lane >> 4;

    int id = blockIdx.x;                    // 1024 blocks
    id = (id & 7) * 128 + (id >> 3);        // 4 (b,h) groups per XCD (K/V ~2MB, L2-fit)
    const int qt = id & 31, h = (id >> 5) & 15, b = id >> 9;
    const int q0 = qt * 64 + wv * 16;

    __shared__ alignas(16) u16 Kbuf[2][4096];   // 8KB x2: 8 chunks x (64 rows x 8 u16)
    __shared__ alignas(16) u16 Vbuf[2][4096];   // 8KB x2
    __shared__ alignas(16) u16 Ps[4][2][1024];  // per-wave P tiles
    u16* P1 = &Ps[wv][0][0];
    u16* P2 = &Ps[wv][1][0];

    float s1 = 0.f, s2 = 0.f;
#pragma unroll
    for (int i = 0; i < 32; ++i) { s1 += lq1[i] * lk1[i]; s2 += lq2[i] * lk2[i]; }
    const float lam = __expf(s1) - __expf(s2) + LAMBDA_INIT;

    const u16* Qbase = Qb + (size_t)b * NQ * DIMC;
    const u16* Krow = Kb + (size_t)b * NK * DIMC + (size_t)lane * DIMC + h * 32;
    const u16* Vrow = Vt + (size_t)h * 64 * 4096 + (size_t)b * 2048 + (size_t)lane * 4096;

    const bf16x8 q1f = *(const bf16x8*)(Qbase + (size_t)(q0 + l15) * DIMC + h * 32 + 8 * l4);
    const bf16x8 q2f = *(const bf16x8*)(Qbase + (size_t)(q0 + l15) * DIMC + 512 + h * 32 + 8 * l4);

    float m1 = -1e30f, d1 = 0.f, m2 = -1e30f, d2 = 0.f;
    f32x4 acc1[4], acc2[4];
    f32x4 zf = {0.f, 0.f, 0.f, 0.f};
#pragma unroll
    for (int t = 0; t < 4; ++t) { acc1[t] = zf; acc2[t] = zf; }

    const int wrow = l4 << 2;

    auto STAGE = [&](int nb, int kv) {
#pragma unroll
        for (int g = 0; g < 2; ++g) {
            const int c = g * 4 + wv;
            const int koff = (c < 4) ? c * 8 : 512 + (c - 4) * 8;
            gload_lds16(Krow + (size_t)kv * DIMC + koff, &Kbuf[nb][c * 512]);
            gload_lds16(Vrow + kv + c * 8,               &Vbuf[nb][c * 512]);
        }
    };

    STAGE(0, 0);
    __syncthreads();

    int buf = 0;
    for (int t = 0; t < 32; ++t) {
        if (t < 31) STAGE(buf ^ 1, (t + 1) * 64);

        const u16* Kl = &Kbuf[buf][0];
        const u16* Vl = &Vbuf[buf][0];

        f32x4 sc1[4], sc2[4];
#pragma unroll
        for (int s = 0; s < 4; ++s) {
            bf16x8 k1 = *(const bf16x8*)(Kl + l4 * 512 + (s * 16 + l15) * 8);
            bf16x8 k2 = *(const bf16x8*)(Kl + (4 + l4) * 512 + (s * 16 + l15) * 8);
            sc1[s] = __builtin_amdgcn_mfma_f32_16x16x32_bf16(k1, q1f, zf, 0, 0, 0);
            sc2[s] = __builtin_amdgcn_mfma_f32_16x16x32_bf16(k2, q2f, zf, 0, 0, 0);
        }

        // ---- softmax attn 1 (defer-max, exp2) ----
        {
            float pm = sc1[0][0];
#pragma unroll
            for (int s = 0; s < 4; ++s)
#pragma unroll
                for (int r = 0; r < 4; ++r) pm = fmaxf(pm, sc1[s][r]);
            pm = fmaxf(pm, __shfl_xor(pm, 16));
            pm = fmaxf(pm, __shfl_xor(pm, 32));
            if (!__all(pm - m1 <= 8.f)) {
                const float mnew = fmaxf(m1, pm);
                const float alpha = __builtin_amdgcn_exp2f(m1 - mnew);
                m1 = mnew;
                d1 *= alpha;
                float ar[4];
#pragma unroll
                for (int r = 0; r < 4; ++r) ar[r] = __shfl(alpha, wrow + r);
#pragma unroll
                for (int tt = 0; tt < 4; ++tt)
#pragma unroll
                    for (int r = 0; r < 4; ++r) acc1[tt][r] *= ar[r];
            }
            float rs = 0.f;
            float p[4][4];
#pragma unroll
            for (int s = 0; s < 4; ++s)
#pragma unroll
                for (int r = 0; r < 4; ++r) {
                    p[s][r] = __builtin_amdgcn_exp2f(sc1[s][r] - m1);
                    rs += p[s][r];
                }
            rs += __shfl_xor(rs, 16);
            rs += __shfl_xor(rs, 32);
            d1 += rs;
#pragma unroll
            for (int s = 0; s < 4; ++s) {
                uint2 wvv;
                wvv.x = packbf_trunc(p[s][0], p[s][1]);
                wvv.y = packbf_trunc(p[s][2], p[s][3]);
                const int idx = ((l15 << 6) + (s << 4) + (l4 << 2)) ^ ((l15 & 7) << 3);
                *(uint2*)&P1[idx] = wvv;
            }
        }
        // ---- softmax attn 2 ----
        {
            float pm = sc2[0][0];
#pragma unroll
            for (int s = 0; s < 4; ++s)
#pragma unroll
                for (int r = 0; r < 4; ++r) pm = fmaxf(pm, sc2[s][r]);
            pm = fmaxf(pm, __shfl_xor(pm, 16));
            pm = fmaxf(pm, __shfl_xor(pm, 32));
            if (!__all(pm - m2 <= 8.f)) {
                const float mnew = fmaxf(m2, pm);
                const float alpha = __builtin_amdgcn_exp2f(m2 - mnew);
                m2 = mnew;
                d2 *= alpha;
                float ar[4];
#pragma unroll
                for (int r = 0; r < 4; ++r) ar[r] = __shfl(alpha, wrow + r);
#pragma unroll
                for (int tt = 0; tt < 4; ++tt)
#pragma unroll
                    for (int r = 0; r < 4; ++r) acc2[tt][r] *= ar[r];
            }
            float rs = 0.f;
            float p[4][4];
#pragma unroll
            for (int s = 0; s < 4; ++s)
#pragma unroll
                for (int r = 0; r < 4; ++r) {
                    p[s][r] = __builtin_amdgcn_exp2f(sc2[s][r] - m2);
                    rs += p[s][r];
                }
            rs += __shfl_xor(rs, 16);
            rs += __shfl_xor(rs, 32);
            d2 += rs;
#pragma unroll
            for (int s = 0; s < 4; ++s) {
                uint2 wvv;
                wvv.x = packbf_trunc(p[s][0], p[s][1]);
                wvv.y = packbf_trunc(p[s][2], p[s][3]);
                const int idx = ((l15 << 6) + (s << 4) + (l4 << 2)) ^ ((l15 & 7) << 3);
                *(uint2*)&P2[idx] = wvv;
            }
        }

        // ---- PV from LDS ----
#pragma unroll
        for (int kc = 0; kc < 2; ++kc) {
            const int ridx = ((l15 << 6) + (kc << 5) + (l4 << 3)) ^ ((l15 & 7) << 3);
            const bf16x8 p1a = *(const bf16x8*)&P1[ridx];
            const bf16x8 p2a = *(const bf16x8*)&P2[ridx];
#pragma unroll
            for (int tt = 0; tt < 4; ++tt) {
                bf16x8 vb = *(const bf16x8*)(Vl + (kc * 4 + l4) * 512 + (tt * 16 + l15) * 8);
                acc1[tt] = __builtin_amdgcn_mfma_f32_16x16x32_bf16(p1a, vb, acc1[tt], 0, 0, 0);
                acc2[tt] = __builtin_amdgcn_mfma_f32_16x16x32_bf16(p2a, vb, acc2[tt], 0, 0, 0);
            }
        }

        __syncthreads();
        buf ^= 1;
    }

    // epilogue
    float i1[4], i2[4];
#pragma unroll
    for (int r = 0; r < 4; ++r) {
        i1[r] = 1.f / __shfl(d1, wrow + r);
        i2[r] = 1.f / __shfl(d2, wrow + r);
    }

    float vals[4][4];
    float ss[4] = {0.f, 0.f, 0.f, 0.f};
#pragma unroll
    for (int t = 0; t < 4; ++t)
#pragma unroll
        for (int r = 0; r < 4; ++r) {
            const float v = acc1[t][r] * i1[r] - lam * (acc2[t][r] * i2[r]);
            vals[t][r] = v;
            ss[r] += v * v;
        }
#pragma unroll
    for (int r = 0; r < 4; ++r) {
        float s = ss[r];
        s += __shfl_xor(s, 1); s += __shfl_xor(s, 2);
        s += __shfl_xor(s, 4); s += __shfl_xor(s, 8);
        ss[r] = rsqrtf(s * (1.f / 64.f) + EPS_) * ONE_MINUS_LI;
    }
#pragma unroll
    for (int t = 0; t < 4; ++t)
#pragma unroll
        for (int r = 0; r < 4; ++r) {
            const int col = t * 16 + l15;
            const int row = q0 + wrow + r;
            const float o = vals[t][r] * ss[r] * subln[col];
            X2[(size_t)(b * NQ + row) * DIMC + h * 64 + col] = f2bf(o);
        }
}

extern "C" void kernel_launch(void* const* d_in, const int* in_sizes, int n_in,
                              void* d_out, int out_size, void* d_ws, size_t ws_size,
                              hipStream_t stream) {
    const float* query = (const float*)d_in[0];
    const float* key_  = (const float*)d_in[1];
    const float* value = (const float*)d_in[2];
    const float* Wq    = (const float*)d_in[3];
    const float* Wk    = (const float*)d_in[4];
    const float* Wv    = (const float*)d_in[5];
    const float* Wp    = (const float*)d_in[6];
    const float* bp    = (const float*)d_in[7];
    const float* lq1   = (const float*)d_in[8];
    const float* lk1   = (const float*)d_in[9];
    const float* lq2   = (const float*)d_in[10];
    const float* lk2   = (const float*)d_in[11];
    const float* subln = (const float*)d_in[12];
    float* out = (float*)d_out;

    const size_t MB4 = (size_t)4096 * 1024;   // 4M elems
    const size_t MB1 = (size_t)1024 * 1024;   // 1M elems
    u16* base = (u16*)d_ws;
    u16* qbf = base;                 // 4M
    u16* kbf = qbf + MB4;            // 4M
    u16* vbf = kbf + MB4;            // 4M  (reused as X2 after QKV gemm)
    u16* wqb = vbf + MB4;            // 1M
    u16* wkb = wqb + MB1;            // 1M
    u16* wvb = wkb + MB1;            // 1M
    u16* wpb = wvb + MB1;            // 1M
    u16* Qb  = wpb + MB1;            // 4M
    u16* Kb  = Qb + MB4;             // 4M
    u16* Vt  = Kb + MB4;             // 4M  [1024 dims][4096 tokens]
    u16* X2  = vbf;                  // alias: vbf dead after qkv gemm

    dim3 bb(256, 1, 1);
    // all f32 -> bf16 conversions in one launch
    hipLaunchKernelGGL(cvt_all_kernel, dim3(8192), bb, 0, stream,
                       query, key_, value, Wq, Wk, Wv, Wp,
                       qbf, kbf, vbf, wqb, wkb, wvb, wpb);

    // fused QKV projections (Q pre-scaled by SCALE*log2e); V transposed via swapped operands
    hipLaunchKernelGGL(qkv_gemm_kernel, dim3(8, 32, 3), bb, 0, stream,
                       qbf, wqb, Qb, kbf, wkb, Kb, wvb, vbf, Vt, SCALE_ * LOG2E_);

    hipLaunchKernelGGL(attn_kernel, dim3(1024), bb, 0, stream,
                       Qb, Kb, Vt, lq1, lk1, lq2, lk2, subln, X2);

    hipLaunchKernelGGL(out_gemm_kernel, dim3(8, 32, 1), bb, 0, stream, X2, wpb, out, bp);
}